// Round 1
// baseline (838.596 us; speedup 1.0000x reference)
//
#include <hip/hip_runtime.h>
#include <math.h>

#define GN 50000
#define GE 800000
#define INF 128
#define OUTF 64
#define LRELU_ALPHA 0.2f

// ---------------------------------------------------------------------------
// K0: zero the softmax denominator and the output accumulator (ws/out are
// poisoned 0xAA before every timed launch).
// ---------------------------------------------------------------------------
__global__ __launch_bounds__(256) void k_zero(float* __restrict__ denom,
                                              float* __restrict__ out) {
    int i = blockIdx.x * 256 + threadIdx.x;
    if (i < GN) denom[i] = 0.0f;
    if (i < GN * OUTF) out[i] = 0.0f;
}

// ---------------------------------------------------------------------------
// K1: Wh = h @ W  (N x 128 @ 128 x 64), fused s1 = Wh@a1, s2 = Wh@a2.
// 256 threads/block = 16 nodes/block, 16 lanes per node, 4 feats per lane.
// W staged in LDS (32 KB), all float4.
// ---------------------------------------------------------------------------
__global__ __launch_bounds__(256) void k_gemm(const float* __restrict__ h,
                                              const float* __restrict__ W,
                                              const float* __restrict__ a,
                                              float* __restrict__ Wh,
                                              float* __restrict__ s1,
                                              float* __restrict__ s2) {
    __shared__ __align__(16) float Wlds[INF * OUTF];  // 32 KB
    int t = threadIdx.x;
    for (int i = t * 4; i < INF * OUTF; i += 256 * 4) {
        *(float4*)&Wlds[i] = *(const float4*)&W[i];
    }
    __syncthreads();

    int node = blockIdx.x * 16 + (t >> 4);   // 3125 blocks * 16 = 50000 exactly
    int jg   = (t & 15) * 4;                 // feature group base (0..60)
    if (node >= GN) return;

    const float4* h4 = (const float4*)&h[node * INF];
    float4 acc = {0.f, 0.f, 0.f, 0.f};
    #pragma unroll
    for (int k4 = 0; k4 < INF / 4; ++k4) {
        float4 hv = h4[k4];
        int k = k4 * 4;
        float4 w0 = *(float4*)&Wlds[(k + 0) * OUTF + jg];
        float4 w1 = *(float4*)&Wlds[(k + 1) * OUTF + jg];
        float4 w2 = *(float4*)&Wlds[(k + 2) * OUTF + jg];
        float4 w3 = *(float4*)&Wlds[(k + 3) * OUTF + jg];
        acc.x += hv.x * w0.x + hv.y * w1.x + hv.z * w2.x + hv.w * w3.x;
        acc.y += hv.x * w0.y + hv.y * w1.y + hv.z * w2.y + hv.w * w3.y;
        acc.z += hv.x * w0.z + hv.y * w1.z + hv.z * w2.z + hv.w * w3.z;
        acc.w += hv.x * w0.w + hv.y * w1.w + hv.z * w2.w + hv.w * w3.w;
    }
    *(float4*)&Wh[node * OUTF + jg] = acc;

    // partial dot with a1/a2, reduce across the 16 lanes of this node
    float p1 = acc.x * a[jg]        + acc.y * a[jg + 1]
             + acc.z * a[jg + 2]    + acc.w * a[jg + 3];
    float p2 = acc.x * a[OUTF + jg]     + acc.y * a[OUTF + jg + 1]
             + acc.z * a[OUTF + jg + 2] + acc.w * a[OUTF + jg + 3];
    #pragma unroll
    for (int off = 8; off >= 1; off >>= 1) {
        p1 += __shfl_down(p1, off, 16);
        p2 += __shfl_down(p2, off, 16);
    }
    if ((t & 15) == 0) {
        s1[node] = p1;
        s2[node] = p2;
    }
}

// ---------------------------------------------------------------------------
// K2: per-edge score -> exp -> denominator accumulation.
// ---------------------------------------------------------------------------
__global__ __launch_bounds__(256) void k_edge(const int* __restrict__ src,
                                              const int* __restrict__ dst,
                                              const float* __restrict__ s1,
                                              const float* __restrict__ s2,
                                              float* __restrict__ expe,
                                              float* __restrict__ denom) {
    int e = blockIdx.x * 256 + threadIdx.x;
    if (e >= GE) return;
    int s = src[e], d = dst[e];
    float x = s1[s] + s2[d];
    x = (x > 0.f) ? x : LRELU_ALPHA * x;
    float ex = expf(x);
    expe[e] = ex;
    atomicAdd(&denom[d], ex);
}

// ---------------------------------------------------------------------------
// K3: scatter attention * Wh[src] into out[dst]. Thread = (edge, 4-feat group).
// ---------------------------------------------------------------------------
__global__ __launch_bounds__(256) void k_scatter(const int* __restrict__ src,
                                                 const int* __restrict__ dst,
                                                 const float* __restrict__ expe,
                                                 const float* __restrict__ denom,
                                                 const float* __restrict__ Wh,
                                                 float* __restrict__ out) {
    long tid = (long)blockIdx.x * 256 + threadIdx.x;  // GE*16 threads
    int e  = (int)(tid >> 4);
    int jg = ((int)tid & 15) * 4;
    if (e >= GE) return;
    int d = dst[e];
    float att = expe[e] / denom[d];
    float4 wv = *(const float4*)&Wh[src[e] * OUTF + jg];
    float* o = &out[d * OUTF + jg];
    atomicAdd(o + 0, att * wv.x);
    atomicAdd(o + 1, att * wv.y);
    atomicAdd(o + 2, att * wv.z);
    atomicAdd(o + 3, att * wv.w);
}

// ---------------------------------------------------------------------------
// K4: ELU epilogue in place on out.
// ---------------------------------------------------------------------------
__global__ __launch_bounds__(256) void k_elu(float* __restrict__ out) {
    int i = blockIdx.x * 256 + threadIdx.x;
    if (i >= GN * OUTF) return;
    float x = out[i];
    out[i] = (x > 0.f) ? x : expm1f(x);
}

extern "C" void kernel_launch(void* const* d_in, const int* in_sizes, int n_in,
                              void* d_out, int out_size, void* d_ws, size_t ws_size,
                              hipStream_t stream) {
    const float* h  = (const float*)d_in[0];
    const int*   ei = (const int*)d_in[1];    // [2, E]: first E = src, next E = dst
    const float* W  = (const float*)d_in[2];
    const float* a  = (const float*)d_in[3];
    const int* src = ei;
    const int* dst = ei + GE;

    float* ws = (float*)d_ws;
    float* s1    = ws;                 // N
    float* s2    = s1 + GN;            // N
    float* denom = s2 + GN;            // N
    float* expe  = denom + GN;         // E
    float* Wh    = expe + GE;          // N*64
    float* out   = (float*)d_out;      // N*64 (also the accumulator)

    // K0: zero denom + out
    k_zero<<<(GN * OUTF + 255) / 256, 256, 0, stream>>>(denom, out);
    // K1: Wh, s1, s2
    k_gemm<<<(GN + 15) / 16, 256, 0, stream>>>(h, W, a, Wh, s1, s2);
    // K2: exp(leakyrelu) + denom
    k_edge<<<(GE + 255) / 256, 256, 0, stream>>>(src, dst, s1, s2, expe, denom);
    // K3: scatter messages
    long sc_threads = (long)GE * 16;
    k_scatter<<<(int)((sc_threads + 255) / 256), 256, 0, stream>>>(src, dst, expe,
                                                                  denom, Wh, out);
    // K4: ELU
    k_elu<<<(GN * OUTF + 255) / 256, 256, 0, stream>>>(out);
}

// Round 2
// 303.341 us; speedup vs baseline: 2.7645x; 2.7645x over previous
//
#include <hip/hip_runtime.h>
#include <math.h>

#define GN 50000
#define GE 800000
#define INF 128
#define OUTF 64
#define LRELU_ALPHA 0.2f
#define SCAN_T 1024

// ---------------------------------------------------------------------------
// K0: zero the per-dst edge counts (ws is poisoned 0xAA before every call).
// ---------------------------------------------------------------------------
__global__ __launch_bounds__(256) void k_zero(int* __restrict__ counts) {
    int i = blockIdx.x * 256 + threadIdx.x;
    if (i < GN) counts[i] = 0;
}

// ---------------------------------------------------------------------------
// K1: Wh = h @ W  (N x 128 @ 128 x 64), fused s1 = Wh@a1, s2 = Wh@a2.
// 16 nodes/block, 16 lanes per node, 4 feats per lane. W staged in LDS.
// ---------------------------------------------------------------------------
__global__ __launch_bounds__(256) void k_gemm(const float* __restrict__ h,
                                              const float* __restrict__ W,
                                              const float* __restrict__ a,
                                              float* __restrict__ Wh,
                                              float* __restrict__ s1,
                                              float* __restrict__ s2) {
    __shared__ __align__(16) float Wlds[INF * OUTF];  // 32 KB
    int t = threadIdx.x;
    for (int i = t * 4; i < INF * OUTF; i += 256 * 4) {
        *(float4*)&Wlds[i] = *(const float4*)&W[i];
    }
    __syncthreads();

    int node = blockIdx.x * 16 + (t >> 4);   // 3125 blocks * 16 = 50000 exactly
    int jg   = (t & 15) * 4;
    if (node >= GN) return;

    const float4* h4 = (const float4*)&h[node * INF];
    float4 acc = {0.f, 0.f, 0.f, 0.f};
    #pragma unroll
    for (int k4 = 0; k4 < INF / 4; ++k4) {
        float4 hv = h4[k4];
        int k = k4 * 4;
        float4 w0 = *(float4*)&Wlds[(k + 0) * OUTF + jg];
        float4 w1 = *(float4*)&Wlds[(k + 1) * OUTF + jg];
        float4 w2 = *(float4*)&Wlds[(k + 2) * OUTF + jg];
        float4 w3 = *(float4*)&Wlds[(k + 3) * OUTF + jg];
        acc.x += hv.x * w0.x + hv.y * w1.x + hv.z * w2.x + hv.w * w3.x;
        acc.y += hv.x * w0.y + hv.y * w1.y + hv.z * w2.y + hv.w * w3.y;
        acc.z += hv.x * w0.z + hv.y * w1.z + hv.z * w2.z + hv.w * w3.z;
        acc.w += hv.x * w0.w + hv.y * w1.w + hv.z * w2.w + hv.w * w3.w;
    }
    *(float4*)&Wh[node * OUTF + jg] = acc;

    float p1 = acc.x * a[jg]        + acc.y * a[jg + 1]
             + acc.z * a[jg + 2]    + acc.w * a[jg + 3];
    float p2 = acc.x * a[OUTF + jg]     + acc.y * a[OUTF + jg + 1]
             + acc.z * a[OUTF + jg + 2] + acc.w * a[OUTF + jg + 3];
    #pragma unroll
    for (int off = 8; off >= 1; off >>= 1) {
        p1 += __shfl_down(p1, off, 16);
        p2 += __shfl_down(p2, off, 16);
    }
    if ((t & 15) == 0) {
        s1[node] = p1;
        s2[node] = p2;
    }
}

// ---------------------------------------------------------------------------
// K2: histogram of dst -> counts.
// ---------------------------------------------------------------------------
__global__ __launch_bounds__(256) void k_hist(const int* __restrict__ dst,
                                              int* __restrict__ counts) {
    int e = blockIdx.x * 256 + threadIdx.x;
    if (e < GE) atomicAdd(&counts[dst[e]], 1);
}

// ---------------------------------------------------------------------------
// K3: single-block exclusive scan of counts[0..GN) -> row_start[0..GN).
// row_start[n] = start offset of node n's bucket.
// ---------------------------------------------------------------------------
__global__ __launch_bounds__(SCAN_T) void k_scan(const int* __restrict__ counts,
                                                 int* __restrict__ row_start) {
    __shared__ int part[SCAN_T];
    int t = threadIdx.x;
    const int CH = (GN + SCAN_T - 1) / SCAN_T;  // 49
    int lo = t * CH;
    int hi = lo + CH; if (hi > GN) hi = GN;
    int s = 0;
    for (int i = lo; i < hi; ++i) s += counts[i];
    part[t] = s;
    __syncthreads();
    // Hillis-Steele inclusive scan over the 1024 partials
    for (int off = 1; off < SCAN_T; off <<= 1) {
        int v = (t >= off) ? part[t - off] : 0;
        __syncthreads();
        part[t] += v;
        __syncthreads();
    }
    int run = (t > 0) ? part[t - 1] : 0;   // exclusive prefix of this chunk
    for (int i = lo; i < hi; ++i) {
        row_start[i] = run;
        run += counts[i];
    }
}

// ---------------------------------------------------------------------------
// K4: fill buckets. atomicAdd on row_start doubles as the cursor; afterwards
// row_start[n] == original start of node n+1 (i.e. end of node n).
// ---------------------------------------------------------------------------
__global__ __launch_bounds__(256) void k_bucket(const int* __restrict__ src,
                                                const int* __restrict__ dst,
                                                int* __restrict__ row_start,
                                                int* __restrict__ esrc) {
    int e = blockIdx.x * 256 + threadIdx.x;
    if (e >= GE) return;
    int d = dst[e];
    int pos = atomicAdd(&row_start[d], 1);
    esrc[pos] = src[e];
}

// ---------------------------------------------------------------------------
// K5: fused softmax + aggregation + ELU, one pass per dst node, no atomics.
// 16 lanes per node (4 feats each), 16 nodes per 256-thread block.
// After k_bucket: end(n) = row_start[n], start(n) = n ? row_start[n-1] : 0.
// ---------------------------------------------------------------------------
__global__ __launch_bounds__(256) void k_gather(const int* __restrict__ row_start,
                                                const int* __restrict__ esrc,
                                                const float* __restrict__ s1,
                                                const float* __restrict__ s2,
                                                const float* __restrict__ Wh,
                                                float* __restrict__ out) {
    int t = threadIdx.x;
    int node = blockIdx.x * 16 + (t >> 4);
    if (node >= GN) return;
    int jg = (t & 15) * 4;

    int end   = row_start[node];
    int start = (node > 0) ? row_start[node - 1] : 0;
    float s2n = s2[node];

    float4 acc = {0.f, 0.f, 0.f, 0.f};
    float den = 0.f;
    for (int i = start; i < end; ++i) {
        int s = esrc[i];                       // broadcast across the 16 lanes
        float x = s1[s] + s2n;
        x = (x > 0.f) ? x : LRELU_ALPHA * x;
        float ex = expf(x);
        den += ex;
        float4 wv = *(const float4*)&Wh[s * OUTF + jg];
        acc.x += ex * wv.x;
        acc.y += ex * wv.y;
        acc.z += ex * wv.z;
        acc.w += ex * wv.w;
    }
    float inv = (end > start) ? 1.f / den : 0.f;
    float4 o;
    o.x = acc.x * inv; o.y = acc.y * inv; o.z = acc.z * inv; o.w = acc.w * inv;
    o.x = (o.x > 0.f) ? o.x : expm1f(o.x);
    o.y = (o.y > 0.f) ? o.y : expm1f(o.y);
    o.z = (o.z > 0.f) ? o.z : expm1f(o.z);
    o.w = (o.w > 0.f) ? o.w : expm1f(o.w);
    *(float4*)&out[node * OUTF + jg] = o;
}

extern "C" void kernel_launch(void* const* d_in, const int* in_sizes, int n_in,
                              void* d_out, int out_size, void* d_ws, size_t ws_size,
                              hipStream_t stream) {
    const float* h  = (const float*)d_in[0];
    const int*   ei = (const int*)d_in[1];    // [2, E]: first E = src, next E = dst
    const float* W  = (const float*)d_in[2];
    const float* a  = (const float*)d_in[3];
    const int* src = ei;
    const int* dst = ei + GE;

    float* ws = (float*)d_ws;
    float* s1 = ws;                    // N
    float* s2 = s1 + GN;               // N
    float* Wh = s2 + GN;               // N*64
    int* row_start = (int*)(Wh + (size_t)GN * OUTF);  // N
    int* esrc      = row_start + GN;   // E
    int* counts    = esrc;             // alias: counts dead before esrc written
    float* out = (float*)d_out;

    k_zero<<<(GN + 255) / 256, 256, 0, stream>>>(counts);
    k_gemm<<<(GN + 15) / 16, 256, 0, stream>>>(h, W, a, Wh, s1, s2);
    k_hist<<<(GE + 255) / 256, 256, 0, stream>>>(dst, counts);
    k_scan<<<1, SCAN_T, 0, stream>>>(counts, row_start);
    k_bucket<<<(GE + 255) / 256, 256, 0, stream>>>(src, dst, row_start, esrc);
    k_gather<<<(GN + 15) / 16, 256, 0, stream>>>(row_start, esrc, s1, s2, Wh, out);
}

// Round 3
// 220.495 us; speedup vs baseline: 3.8032x; 1.3757x over previous
//
#include <hip/hip_runtime.h>
#include <math.h>

#define GN 50000
#define GE 800000
#define INF 128
#define OUTF 64
#define LRELU_ALPHA 0.2f
#define SCB ((GN + 255) / 256)   // 196 scan blocks

// ---------------------------------------------------------------------------
// K0: zero the per-dst edge counts.
// ---------------------------------------------------------------------------
__global__ __launch_bounds__(256) void k_zero(int* __restrict__ counts) {
    int i = blockIdx.x * 256 + threadIdx.x;
    if (i < GN) counts[i] = 0;
}

// ---------------------------------------------------------------------------
// K1: Wh = h @ W (N x 128 @ 128 x 64), fused s1 = Wh@a1, s2 = Wh@a2.
// 16 nodes/block, 16 lanes/node, 4 feats/lane. W staged in LDS.
// ---------------------------------------------------------------------------
__global__ __launch_bounds__(256) void k_gemm(const float* __restrict__ h,
                                              const float* __restrict__ W,
                                              const float* __restrict__ a,
                                              float* __restrict__ Wh,
                                              float* __restrict__ s1,
                                              float* __restrict__ s2) {
    __shared__ __align__(16) float Wlds[INF * OUTF];  // 32 KB
    int t = threadIdx.x;
    for (int i = t * 4; i < INF * OUTF; i += 256 * 4) {
        *(float4*)&Wlds[i] = *(const float4*)&W[i];
    }
    __syncthreads();

    int node = blockIdx.x * 16 + (t >> 4);
    int jg   = (t & 15) * 4;
    if (node >= GN) return;

    const float4* h4 = (const float4*)&h[node * INF];
    float4 acc = {0.f, 0.f, 0.f, 0.f};
    #pragma unroll
    for (int k4 = 0; k4 < INF / 4; ++k4) {
        float4 hv = h4[k4];
        int k = k4 * 4;
        float4 w0 = *(float4*)&Wlds[(k + 0) * OUTF + jg];
        float4 w1 = *(float4*)&Wlds[(k + 1) * OUTF + jg];
        float4 w2 = *(float4*)&Wlds[(k + 2) * OUTF + jg];
        float4 w3 = *(float4*)&Wlds[(k + 3) * OUTF + jg];
        acc.x += hv.x * w0.x + hv.y * w1.x + hv.z * w2.x + hv.w * w3.x;
        acc.y += hv.x * w0.y + hv.y * w1.y + hv.z * w2.y + hv.w * w3.y;
        acc.z += hv.x * w0.z + hv.y * w1.z + hv.z * w2.z + hv.w * w3.z;
        acc.w += hv.x * w0.w + hv.y * w1.w + hv.z * w2.w + hv.w * w3.w;
    }
    *(float4*)&Wh[node * OUTF + jg] = acc;

    float p1 = acc.x * a[jg]        + acc.y * a[jg + 1]
             + acc.z * a[jg + 2]    + acc.w * a[jg + 3];
    float p2 = acc.x * a[OUTF + jg]     + acc.y * a[OUTF + jg + 1]
             + acc.z * a[OUTF + jg + 2] + acc.w * a[OUTF + jg + 3];
    #pragma unroll
    for (int off = 8; off >= 1; off >>= 1) {
        p1 += __shfl_down(p1, off, 16);
        p2 += __shfl_down(p2, off, 16);
    }
    if ((t & 15) == 0) {
        s1[node] = p1;
        s2[node] = p2;
    }
}

// ---------------------------------------------------------------------------
// K2: histogram of dst -> counts.
// ---------------------------------------------------------------------------
__global__ __launch_bounds__(256) void k_hist(const int* __restrict__ dst,
                                              int* __restrict__ counts) {
    int e = blockIdx.x * 256 + threadIdx.x;
    if (e < GE) atomicAdd(&counts[dst[e]], 1);
}

// ---------------------------------------------------------------------------
// K3a: per-block reduce of counts -> bsum[block].
// ---------------------------------------------------------------------------
__global__ __launch_bounds__(256) void k_scan1(const int* __restrict__ counts,
                                               int* __restrict__ bsum) {
    __shared__ int lds[256];
    int t = threadIdx.x;
    int i = blockIdx.x * 256 + t;
    lds[t] = (i < GN) ? counts[i] : 0;
    __syncthreads();
    #pragma unroll
    for (int off = 128; off >= 1; off >>= 1) {
        if (t < off) lds[t] += lds[t + off];
        __syncthreads();
    }
    if (t == 0) bsum[blockIdx.x] = lds[0];
}

// ---------------------------------------------------------------------------
// K3b: single block, exclusive scan of the SCB block sums -> boff.
// ---------------------------------------------------------------------------
__global__ __launch_bounds__(256) void k_scan2(const int* __restrict__ bsum,
                                               int* __restrict__ boff) {
    __shared__ int lds[256];
    int t = threadIdx.x;
    int v = (t < SCB) ? bsum[t] : 0;
    lds[t] = v;
    __syncthreads();
    #pragma unroll
    for (int off = 1; off < 256; off <<= 1) {
        int u = (t >= off) ? lds[t - off] : 0;
        __syncthreads();
        lds[t] += u;
        __syncthreads();
    }
    if (t < SCB) boff[t] = lds[t] - v;   // exclusive
}

// ---------------------------------------------------------------------------
// K3c: per-block local exclusive scan + block offset -> row_start.
// ---------------------------------------------------------------------------
__global__ __launch_bounds__(256) void k_scan3(const int* __restrict__ counts,
                                               const int* __restrict__ boff,
                                               int* __restrict__ row_start) {
    __shared__ int lds[256];
    int t = threadIdx.x;
    int i = blockIdx.x * 256 + t;
    int v = (i < GN) ? counts[i] : 0;
    lds[t] = v;
    __syncthreads();
    #pragma unroll
    for (int off = 1; off < 256; off <<= 1) {
        int u = (t >= off) ? lds[t - off] : 0;
        __syncthreads();
        lds[t] += u;
        __syncthreads();
    }
    if (i < GN) row_start[i] = boff[blockIdx.x] + lds[t] - v;
}

// ---------------------------------------------------------------------------
// K4: fill buckets. atomicAdd on row_start doubles as the cursor; afterwards
// row_start[n] == end offset of node n's bucket.
// ---------------------------------------------------------------------------
__global__ __launch_bounds__(256) void k_bucket(const int* __restrict__ src,
                                                const int* __restrict__ dst,
                                                int* __restrict__ row_start,
                                                int* __restrict__ esrc) {
    int e = blockIdx.x * 256 + threadIdx.x;
    if (e >= GE) return;
    int d = dst[e];
    int pos = atomicAdd(&row_start[d], 1);
    esrc[pos] = src[e];
}

// ---------------------------------------------------------------------------
// K5: fused softmax + aggregation + ELU. 16 lanes/node, 4 feats/lane.
// Edges processed in chunks of 16: lane l computes expf for edge base+l once,
// then all lanes consume it via __shfl (16x less expf work than broadcast).
// ---------------------------------------------------------------------------
__global__ __launch_bounds__(256) void k_gather(const int* __restrict__ row_start,
                                                const int* __restrict__ esrc,
                                                const float* __restrict__ s1,
                                                const float* __restrict__ s2,
                                                const float* __restrict__ Wh,
                                                float* __restrict__ out) {
    int t = threadIdx.x;
    int node = blockIdx.x * 16 + (t >> 4);
    if (node >= GN) return;
    int lane = t & 15;
    int jg = lane * 4;

    int end   = row_start[node];
    int start = (node > 0) ? row_start[node - 1] : 0;
    float s2n = s2[node];

    float4 acc = {0.f, 0.f, 0.f, 0.f};
    float den = 0.f;
    for (int base = start; base < end; base += 16) {
        int my_e = base + lane;
        int idx = my_e < GE ? my_e : GE - 1;       // clamp OOB buffer read
        int s_l = esrc[idx];
        float ex_l = 0.f;
        if (my_e < end) {
            float x = s1[s_l] + s2n;
            x = (x > 0.f) ? x : LRELU_ALPHA * x;
            ex_l = expf(x);
        }
        int cnt = end - base; if (cnt > 16) cnt = 16;
        for (int j = 0; j < cnt; ++j) {
            float ex = __shfl(ex_l, j, 16);
            int   s  = __shfl(s_l, j, 16);
            den += ex;
            float4 wv = *(const float4*)&Wh[s * OUTF + jg];
            acc.x += ex * wv.x;
            acc.y += ex * wv.y;
            acc.z += ex * wv.z;
            acc.w += ex * wv.w;
        }
    }
    float inv = (end > start) ? 1.f / den : 0.f;
    float4 o;
    o.x = acc.x * inv; o.y = acc.y * inv; o.z = acc.z * inv; o.w = acc.w * inv;
    o.x = (o.x > 0.f) ? o.x : expm1f(o.x);
    o.y = (o.y > 0.f) ? o.y : expm1f(o.y);
    o.z = (o.z > 0.f) ? o.z : expm1f(o.z);
    o.w = (o.w > 0.f) ? o.w : expm1f(o.w);
    *(float4*)&out[node * OUTF + jg] = o;
}

extern "C" void kernel_launch(void* const* d_in, const int* in_sizes, int n_in,
                              void* d_out, int out_size, void* d_ws, size_t ws_size,
                              hipStream_t stream) {
    const float* h  = (const float*)d_in[0];
    const int*   ei = (const int*)d_in[1];    // [2, E]: first E = src, next E = dst
    const float* W  = (const float*)d_in[2];
    const float* a  = (const float*)d_in[3];
    const int* src = ei;
    const int* dst = ei + GE;

    float* ws = (float*)d_ws;
    float* s1 = ws;                    // N
    float* s2 = s1 + GN;               // N
    float* Wh = s2 + GN;               // N*64
    int* row_start = (int*)(Wh + (size_t)GN * OUTF);  // N
    int* esrc      = row_start + GN;   // E
    int* counts    = esrc;             // alias: counts dead before esrc written
    int* bsum      = esrc + GE;        // SCB
    int* boff      = bsum + SCB;       // SCB
    float* out = (float*)d_out;

    k_zero<<<(GN + 255) / 256, 256, 0, stream>>>(counts);
    k_gemm<<<(GN + 15) / 16, 256, 0, stream>>>(h, W, a, Wh, s1, s2);
    k_hist<<<(GE + 255) / 256, 256, 0, stream>>>(dst, counts);
    k_scan1<<<SCB, 256, 0, stream>>>(counts, bsum);
    k_scan2<<<1, 256, 0, stream>>>(bsum, boff);
    k_scan3<<<SCB, 256, 0, stream>>>(counts, boff, row_start);
    k_bucket<<<(GE + 255) / 256, 256, 0, stream>>>(src, dst, row_start, esrc);
    k_gather<<<(GN + 15) / 16, 256, 0, stream>>>(row_start, esrc, s1, s2, Wh, out);
}